// Round 5
// baseline (240.026 us; speedup 1.0000x reference)
//
#include <hip/hip_runtime.h>

#define NROWS 8192
#define HID   1024
#define NSAMP 8192
#define LCOLS 8193          // NSAMP + 1
#define NEG_INF_F (-1e37f)

#define SCALE_A 127         // E8M0: 2^0
#define SCALE_B 122         // E8M0: 2^-5  (W rows pre-scaled by 32)

typedef __attribute__((ext_vector_type(4))) int   i32x4;
typedef __attribute__((ext_vector_type(8))) int   i32x8;
typedef __attribute__((ext_vector_type(4))) float f32x4;
typedef f32x4 __attribute__((aligned(4))) f32x4u;   // 4B-aligned vector store
typedef __attribute__((ext_vector_type(8))) __bf16 bf16x8;
typedef __attribute__((ext_vector_type(8))) unsigned short u16x8;

__device__ __forceinline__ unsigned short f2bf(float x) {
  unsigned u = __float_as_uint(x);
  u += 0x7fffu + ((u >> 16) & 1u);
  return (unsigned short)(u >> 16);
}

// ===================== fp8 tiled-workspace layout (lane-linear, verified r3) ==
// Element (row = G*16 + rl, k = kk*128 + kq*32 + h*16 + j) lives at:
//   off = (G*8 + kk)*2048 + h*1024 + kq*256 + rl*16 + j
// MFMA fragment (G, kk, h) for lane l is the 16B at off = ...+ l*16:
// a fragment load is ONE fully-coalesced global_load_dwordx4 (1 KB/wave).
// Same k-permutation for A and B -> dot products unchanged.

__device__ __forceinline__ int pk4(float a, float b, float c, float d) {
  int r = __builtin_amdgcn_cvt_pk_fp8_f32(a, b, 0, 0);
  r = __builtin_amdgcn_cvt_pk_fp8_f32(c, d, r, 1);
  return r;
}

__global__ void k_cvtA(const float* __restrict__ A, unsigned char* __restrict__ Ab) {
  const int t = blockIdx.x * blockDim.x + threadIdx.x;
  const int rl = t & 15, kq = (t >> 4) & 3, h = (t >> 6) & 1;
  const int kk = (t >> 7) & 7, G = t >> 10;
  const int row = G * 16 + rl;
  const int k0 = kk * 128 + kq * 32 + h * 16;
  const float4* s = (const float4*)(A + (size_t)row * HID + k0);
  float4 f0 = s[0], f1 = s[1], f2 = s[2], f3 = s[3];
  int4 o;
  o.x = pk4(f0.x, f0.y, f0.z, f0.w);
  o.y = pk4(f1.x, f1.y, f1.z, f1.w);
  o.z = pk4(f2.x, f2.y, f2.z, f2.w);
  o.w = pk4(f3.x, f3.y, f3.z, f3.w);
  ((int4*)Ab)[t] = o;
}

__global__ void k_gatherB(const float* __restrict__ W, const int* __restrict__ sid,
                          unsigned char* __restrict__ Bb) {
  const int t = blockIdx.x * blockDim.x + threadIdx.x;
  const int rl = t & 15, kq = (t >> 4) & 3, h = (t >> 6) & 1;
  const int kk = (t >> 7) & 7, G = t >> 10;
  const int srow = G * 16 + rl;
  const int id = sid[srow];
  const int k0 = kk * 128 + kq * 32 + h * 16;
  const float4* s = (const float4*)(W + (size_t)id * HID + k0);
  float4 f0 = s[0], f1 = s[1], f2 = s[2], f3 = s[3];
  const float m = 32.0f;   // descaled in-HW by SCALE_B = 2^-5
  int4 o;
  o.x = pk4(f0.x * m, f0.y * m, f0.z * m, f0.w * m);
  o.y = pk4(f1.x * m, f1.y * m, f1.z * m, f1.w * m);
  o.z = pk4(f2.x * m, f2.y * m, f2.z * m, f2.w * m);
  o.w = pk4(f3.x * m, f3.y * m, f3.z * m, f3.w * m);
  ((int4*)Bb)[t] = o;
}

// ------------- true-class logits (column 0) + new_targets ----------------
__global__ void k_true(const float* __restrict__ X, const int* __restrict__ tgt,
                       const float* __restrict__ W, const float* __restrict__ bias,
                       const float* __restrict__ tfreq, float* __restrict__ out) {
  const int n = blockIdx.x * 4 + (threadIdx.x >> 6);
  const int l = threadIdx.x & 63;
  const int tg = tgt[n];
  float4 a = ((const float4*)(X + (size_t)n * HID))[l];
  float4 wv = ((const float4*)(W + (size_t)tg * HID))[l];
  float p = a.x * wv.x + a.y * wv.y + a.z * wv.z + a.w * wv.w;
  #pragma unroll
  for (int off = 32; off > 0; off >>= 1) p += __shfl_down(p, off);
  if (l == 0) {
    out[(size_t)n * LCOLS] = p + bias[tg] - __logf(tfreq[n]);
    ((int*)out)[(size_t)NROWS * LCOLS + n] = 0;
  }
}

// ---- 128x128 MX-fp8 NT-GEMM: barrier-free, direct global->VGPR fragments ----
__global__ __launch_bounds__(256)
void k_gemm8(const unsigned char* __restrict__ Ab, const unsigned char* __restrict__ Bb,
             const int* __restrict__ tgt, const int* __restrict__ sid,
             const float* __restrict__ bias, const float* __restrict__ sfreq,
             float* __restrict__ out) {
  __shared__ unsigned char lds[65536];   // epilogue restage only
  const int t = threadIdx.x, w = t >> 6, l = t & 63;
  int bid = blockIdx.y * 64 + blockIdx.x;
  bid = (bid & 7) * 512 + (bid >> 3);            // XCD swizzle (4096 % 8 == 0)
  const int m0 = (bid >> 6) * 128, n0 = (bid & 63) * 128;
  const int wm = w >> 1, wn = w & 1;
  const int rl = l & 15, kq = l >> 4;
  f32x4 acc[4][4] = {};

  // fragment base: addr(m,kk,h) = pa + (m*8 + kk)*2048 + h*1024
  const unsigned char* pa =
      Ab + ((size_t)((m0 >> 4) + wm * 4) * 8) * 2048 + l * 16;
  const unsigned char* pb =
      Bb + ((size_t)((n0 >> 4) + wn * 4) * 8) * 2048 + l * 16;

  i32x4 aL[2][4], aH[2][4], bL[2][4], bH[2][4];

  // prologue: load kk=0 into buffer 0
  #pragma unroll
  for (int m = 0; m < 4; ++m) {
    aL[0][m] = *(const i32x4*)(pa + m * 16384);
    aH[0][m] = *(const i32x4*)(pa + m * 16384 + 1024);
    bL[0][m] = *(const i32x4*)(pb + m * 16384);
    bH[0][m] = *(const i32x4*)(pb + m * 16384 + 1024);
  }

  #pragma unroll
  for (int kk = 0; kk < 8; ++kk) {
    const int cur = kk & 1, nxt = cur ^ 1;
    // prefetch next K-step's fragments (issued before the MFMA cluster;
    // dependency chain bounds in-flight loads to ~2 steps)
    if (kk < 7) {
      #pragma unroll
      for (int m = 0; m < 4; ++m) {
        aL[nxt][m] = *(const i32x4*)(pa + (m * 8 + kk + 1) * 2048);
        aH[nxt][m] = *(const i32x4*)(pa + (m * 8 + kk + 1) * 2048 + 1024);
        bL[nxt][m] = *(const i32x4*)(pb + (m * 8 + kk + 1) * 2048);
        bH[nxt][m] = *(const i32x4*)(pb + (m * 8 + kk + 1) * 2048 + 1024);
      }
    }
    #pragma unroll
    for (int m = 0; m < 4; ++m) {
      const i32x8 af = (i32x8){aL[cur][m][0], aL[cur][m][1], aL[cur][m][2],
                               aL[cur][m][3], aH[cur][m][0], aH[cur][m][1],
                               aH[cur][m][2], aH[cur][m][3]};
      #pragma unroll
      for (int n = 0; n < 4; ++n) {
        const i32x8 bf = (i32x8){bL[cur][n][0], bL[cur][n][1], bL[cur][n][2],
                                 bL[cur][n][3], bH[cur][n][0], bH[cur][n][1],
                                 bH[cur][n][2], bH[cur][n][3]};
        acc[m][n] = __builtin_amdgcn_mfma_scale_f32_16x16x128_f8f6f4(
            af, bf, acc[m][n], 0, 0, 0, SCALE_A, 0, SCALE_B);
      }
    }
  }

  // ---- epilogue: restage tile in LDS, store 512B-contiguous row segments ----
  // (verified r4: WRITE_SIZE dropped to the 267 MB ideal)
  float* tile = (float*)lds;   // 128 rows x 128 cols f32 = 64 KB
  #pragma unroll
  for (int n = 0; n < 4; ++n) {
    const int col = wn * 64 + n * 16 + rl;         // local col
    const int gcol = n0 + col;
    const int sv = sid[gcol];
    const float sbv = bias[sv] - __logf(sfreq[gcol]);
    #pragma unroll
    for (int m = 0; m < 4; ++m) {
      const int rb = wm * 64 + m * 16 + kq * 4;    // local row base
      #pragma unroll
      for (int i = 0; i < 4; ++i) {
        const int r = rb + i;
        float c = acc[m][n][i] + sbv;
        if (tgt[m0 + r] == sv) c = NEG_INF_F;
        tile[r * 128 + (col ^ ((r & 4) << 2))] = c;   // 2-way banks: free
      }
    }
  }
  __syncthreads();
  #pragma unroll
  for (int p = 0; p < 16; ++p) {
    const int idx = p * 256 + t;
    const int r = idx >> 5;                        // local row
    const int c16 = idx & 31;                      // 16B unit within row
    f32x4 v = *(const f32x4*)&tile[r * 128 + ((c16 * 4) ^ ((r & 4) << 2))];
    *(f32x4u*)&out[(size_t)(m0 + r) * LCOLS + 1 + n0 + c16 * 4] = v;
  }
}

// ---------------- bf16 fallback (round-1 verified), no workspace ----------------
__device__ __forceinline__ void pack8(unsigned short* p, float4 a, float4 b) {
  u16x8 v;
  v[0] = f2bf(a.x); v[1] = f2bf(a.y); v[2] = f2bf(a.z); v[3] = f2bf(a.w);
  v[4] = f2bf(b.x); v[5] = f2bf(b.y); v[6] = f2bf(b.z); v[7] = f2bf(b.w);
  *(u16x8*)p = v;
}

__global__ __launch_bounds__(256)
void k_gemm_fb(const float* __restrict__ Af, const float* __restrict__ W,
               const int* __restrict__ tgt, const int* __restrict__ sid,
               const float* __restrict__ bias, const float* __restrict__ sfreq,
               float* __restrict__ out) {
  __shared__ unsigned short sA[128 * 32];
  __shared__ unsigned short sB[128 * 32];
  const int t = threadIdx.x;
  const int w = t >> 6, l = t & 63;
  const int m0 = blockIdx.y * 128, n0 = blockIdx.x * 128;
  const int wm = w >> 1, wn = w & 1;
  f32x4 acc[4][4] = {};
  const int srow = w * 16 + (l >> 2);
  const int scol = (l & 3) * 8;

  const int id0 = sid[n0 + srow], id1 = sid[n0 + 64 + srow];
  const float* gaf0 = Af + (size_t)(m0 + srow) * HID + scol;
  const float* gaf1 = gaf0 + (size_t)64 * HID;
  const float* gbf0 = W + (size_t)id0 * HID + scol;
  const float* gbf1 = W + (size_t)id1 * HID + scol;
  for (int kk = 0; kk < HID; kk += 32) {
    float4 a0 = *(const float4*)(gaf0 + kk), a1 = *(const float4*)(gaf0 + kk + 4);
    float4 a2 = *(const float4*)(gaf1 + kk), a3 = *(const float4*)(gaf1 + kk + 4);
    float4 b0 = *(const float4*)(gbf0 + kk), b1 = *(const float4*)(gbf0 + kk + 4);
    float4 b2 = *(const float4*)(gbf1 + kk), b3 = *(const float4*)(gbf1 + kk + 4);
    __syncthreads();
    pack8(&sA[t * 8], a0, a1);
    pack8(&sA[2048 + t * 8], a2, a3);
    pack8(&sB[t * 8], b0, b1);
    pack8(&sB[2048 + t * 8], b2, b3);
    __syncthreads();
    bf16x8 af_[4], bf_[4];
    const int rl_ = l & 15, kq_ = l >> 4;
    #pragma unroll
    for (int m = 0; m < 4; m++)
      af_[m] = *(const bf16x8*)&sA[(wm * 64 + m * 16 + rl_) * 32 + kq_ * 8];
    #pragma unroll
    for (int n = 0; n < 4; n++)
      bf_[n] = *(const bf16x8*)&sB[(wn * 64 + n * 16 + rl_) * 32 + kq_ * 8];
    #pragma unroll
    for (int m = 0; m < 4; m++)
      #pragma unroll
      for (int n = 0; n < 4; n++)
        acc[m][n] = __builtin_amdgcn_mfma_f32_16x16x32_bf16(af_[m], bf_[n],
                                                            acc[m][n], 0, 0, 0);
  }
  const int rl = l & 15, rq = l >> 4;
  #pragma unroll
  for (int n = 0; n < 4; ++n) {
    const int col = n0 + wn * 64 + n * 16 + rl;
    const int sv = sid[col];
    const float sbv = bias[sv] - __logf(sfreq[col]);
    #pragma unroll
    for (int m = 0; m < 4; ++m) {
      const int rbase = m0 + wm * 64 + m * 16 + rq * 4;
      #pragma unroll
      for (int i = 0; i < 4; ++i) {
        const int r = rbase + i;
        float c = acc[m][n][i] + sbv;
        if (tgt[r] == sv) c = NEG_INF_F;
        out[(size_t)r * LCOLS + 1 + col] = c;
      }
    }
  }
}

extern "C" void kernel_launch(void* const* d_in, const int* in_sizes, int n_in,
                              void* d_out, int out_size, void* d_ws, size_t ws_size,
                              hipStream_t stream) {
  (void)in_sizes; (void)n_in; (void)out_size;
  const float* output      = (const float*)d_in[0];
  const int*   targets     = (const int*)d_in[1];
  const int*   sample_ids  = (const int*)d_in[2];
  const float* true_freq   = (const float*)d_in[3];
  const float* sample_freq = (const float*)d_in[4];
  const float* weight      = (const float*)d_in[5];
  const float* bias        = (const float*)d_in[6];
  float* out = (float*)d_out;

  const size_t needA = (size_t)NROWS * HID;   // 8 MB fp8
  const size_t needB = (size_t)NSAMP * HID;   // 8 MB fp8
  const bool use_ws = ws_size >= (needA + needB);

  k_true<<<NROWS / 4, 256, 0, stream>>>(output, targets, weight, bias, true_freq, out);

  dim3 grid(NSAMP / 128, NROWS / 128);
  if (use_ws) {
    unsigned char* Ab = (unsigned char*)d_ws;
    unsigned char* Bb = Ab + needA;
    k_cvtA<<<2048, 256, 0, stream>>>(output, Ab);
    k_gatherB<<<2048, 256, 0, stream>>>(weight, sample_ids, Bb);
    k_gemm8<<<grid, 256, 0, stream>>>(Ab, Bb, targets, sample_ids, bias,
                                      sample_freq, out);
  } else {
    k_gemm_fb<<<grid, 256, 0, stream>>>(output, weight, targets, sample_ids,
                                        bias, sample_freq, out);
  }
}

// Round 6
// 165.613 us; speedup vs baseline: 1.4493x; 1.4493x over previous
//
#include <hip/hip_runtime.h>

#define NROWS 8192
#define HID   1024
#define NSAMP 8192
#define LCOLS 8193          // NSAMP + 1
#define NEG_INF_F (-1e37f)

#define SCALE_A 127         // E8M0: 2^0
#define SCALE_B 122         // E8M0: 2^-5  (W rows pre-scaled by 32)

typedef __attribute__((ext_vector_type(4)))  int   i32x4;
typedef __attribute__((ext_vector_type(8)))  int   i32x8;
typedef __attribute__((ext_vector_type(4)))  float f32x4;
typedef __attribute__((ext_vector_type(16))) float f32x16;
typedef f32x4 __attribute__((aligned(4))) f32x4u;   // 4B-aligned vector store
typedef __attribute__((ext_vector_type(8))) __bf16 bf16x8;
typedef __attribute__((ext_vector_type(8))) unsigned short u16x8;

__device__ __forceinline__ unsigned short f2bf(float x) {
  unsigned u = __float_as_uint(x);
  u += 0x7fffu + ((u >> 16) & 1u);
  return (unsigned short)(u >> 16);
}

#define GLOAD_LDS16(g, l)                                                      \
  __builtin_amdgcn_global_load_lds(                                            \
      (const __attribute__((address_space(1))) void*)(g),                      \
      (__attribute__((address_space(3))) void*)(l), 16, 0, 0)

// ============== fp8 workspace layout for 32x32x64 MFMA (lane-linear) =========
// Element (row = G*32 + (l&31), k = KK*64 + ((l>>5)&1)*32 + h*16 + j), j<16:
//   off = (G*16 + KK)*2048 + h*1024 + l*16 + j
// -> every ds_read_b128 is at LDS addr (lane*16): zero bank conflicts
//    (pattern verified r3/r4: SQ_LDS_BANK_CONFLICT == 0).
// -> global_load_lds staging is fully linear (2 KiB contiguous per (G,KK)).
// A and B use the SAME (lane,byte)->k map, so dot products are exact.

__device__ __forceinline__ int pk4(float a, float b, float c, float d) {
  int r = __builtin_amdgcn_cvt_pk_fp8_f32(a, b, 0, 0);
  r = __builtin_amdgcn_cvt_pk_fp8_f32(c, d, r, 1);
  return r;
}

// one thread per 16 ws bytes; 8 MB / 16 = 524288 threads
__global__ void k_cvtA(const float* __restrict__ A, unsigned char* __restrict__ Ab) {
  const int t = blockIdx.x * blockDim.x + threadIdx.x;
  const int l = t & 63, h = (t >> 6) & 1, KK = (t >> 7) & 15, G = t >> 11;
  const int row = G * 32 + (l & 31);
  const int k0 = KK * 64 + ((l >> 5) & 1) * 32 + h * 16;
  const float4* s = (const float4*)(A + (size_t)row * HID + k0);
  float4 f0 = s[0], f1 = s[1], f2 = s[2], f3 = s[3];
  int4 o;
  o.x = pk4(f0.x, f0.y, f0.z, f0.w);
  o.y = pk4(f1.x, f1.y, f1.z, f1.w);
  o.z = pk4(f2.x, f2.y, f2.z, f2.w);
  o.w = pk4(f3.x, f3.y, f3.z, f3.w);
  ((int4*)Ab)[t] = o;
}

__global__ void k_gatherB(const float* __restrict__ W, const int* __restrict__ sid,
                          unsigned char* __restrict__ Bb) {
  const int t = blockIdx.x * blockDim.x + threadIdx.x;
  const int l = t & 63, h = (t >> 6) & 1, KK = (t >> 7) & 15, G = t >> 11;
  const int srow = G * 32 + (l & 31);
  const int id = sid[srow];
  const int k0 = KK * 64 + ((l >> 5) & 1) * 32 + h * 16;
  const float4* s = (const float4*)(W + (size_t)id * HID + k0);
  float4 f0 = s[0], f1 = s[1], f2 = s[2], f3 = s[3];
  const float m = 32.0f;   // descaled in-HW by SCALE_B = 2^-5
  int4 o;
  o.x = pk4(f0.x * m, f0.y * m, f0.z * m, f0.w * m);
  o.y = pk4(f1.x * m, f1.y * m, f1.z * m, f1.w * m);
  o.z = pk4(f2.x * m, f2.y * m, f2.z * m, f2.w * m);
  o.w = pk4(f3.x * m, f3.y * m, f3.z * m, f3.w * m);
  ((int4*)Bb)[t] = o;
}

// ------------- true-class logits (column 0) + new_targets ----------------
__global__ void k_true(const float* __restrict__ X, const int* __restrict__ tgt,
                       const float* __restrict__ W, const float* __restrict__ bias,
                       const float* __restrict__ tfreq, float* __restrict__ out) {
  const int n = blockIdx.x * 4 + (threadIdx.x >> 6);
  const int l = threadIdx.x & 63;
  const int tg = tgt[n];
  float4 a = ((const float4*)(X + (size_t)n * HID))[l];
  float4 wv = ((const float4*)(W + (size_t)tg * HID))[l];
  float p = a.x * wv.x + a.y * wv.y + a.z * wv.z + a.w * wv.w;
  #pragma unroll
  for (int off = 32; off > 0; off >>= 1) p += __shfl_down(p, off);
  if (l == 0) {
    out[(size_t)n * LCOLS] = p + bias[tg] - __logf(tfreq[n]);
    ((int*)out)[(size_t)NROWS * LCOLS + n] = 0;
  }
}

// -- 128x128 MX-fp8 NT-GEMM: 32x32x64 MFMA, BK=64, 32KB LDS, 2-phase pipeline -
__global__ __launch_bounds__(256, 3)
void k_gemm8(const unsigned char* __restrict__ Ab, const unsigned char* __restrict__ Bb,
             const int* __restrict__ tgt, const int* __restrict__ sid,
             const float* __restrict__ bias, const float* __restrict__ sfreq,
             float* __restrict__ out) {
  __shared__ unsigned char lds[32768];   // dbuf 2x(A 8K + B 8K); epilogue: 64x128 f32
  const int t = threadIdx.x, w = t >> 6, l = t & 63;

  // XCD swizzle with 16m x 32n chunks (B working set 4MB = one XCD L2)
  const int orig = blockIdx.y * 64 + blockIdx.x;     // 4096 blocks
  const int c = orig & 7, q = orig >> 3;             // chunk, within-chunk
  const int mi = (c >> 1) * 16 + (q >> 5);
  const int ni = (c & 1) * 32 + (q & 31);
  const int m0 = mi * 128, n0 = ni * 128;
  const int wm = w >> 1, wn = w & 1;
  f32x16 acc[2][2] = {};

  // wave w stages row-group G = (tile base) + w for both A and B
  const unsigned char* gA = Ab + ((size_t)(mi * 4 + w) * 16) * 2048 + l * 16;
  const unsigned char* gB = Bb + ((size_t)(ni * 4 + w) * 16) * 2048 + l * 16;

#define STAGE(buf_, KK_)                                                       \
  do {                                                                         \
    unsigned char* _d = lds + (buf_) * 16384 + w * 2048;                       \
    GLOAD_LDS16(gA + (KK_) * 2048,        _d);                                 \
    GLOAD_LDS16(gA + (KK_) * 2048 + 1024, _d + 1024);                          \
    GLOAD_LDS16(gB + (KK_) * 2048,        _d + 8192);                          \
    GLOAD_LDS16(gB + (KK_) * 2048 + 1024, _d + 8192 + 1024);                   \
  } while (0)

  STAGE(0, 0);
  asm volatile("s_waitcnt vmcnt(0)" ::: "memory");
  __builtin_amdgcn_s_barrier();

  int buf = 0;
  for (int KK = 0; KK < 16; ++KK) {
    // 1) prefetch next K-step into the other buffer (T3 recipe: stage first)
    if (KK < 15) STAGE(buf ^ 1, KK + 1);
    __builtin_amdgcn_sched_barrier(0);

    // 2) fragment ds_reads from current buffer (addr = lane*16, conflict-free)
    const unsigned char* sAb = lds + buf * 16384;
    const unsigned char* sBb = sAb + 8192;
    i32x4 aLo[2], aHi[2], bLo[2], bHi[2];
    #pragma unroll
    for (int mf = 0; mf < 2; ++mf) {
      aLo[mf] = *(const i32x4*)&sAb[(wm * 2 + mf) * 2048 + l * 16];
      aHi[mf] = *(const i32x4*)&sAb[(wm * 2 + mf) * 2048 + 1024 + l * 16];
    }
    #pragma unroll
    for (int nf = 0; nf < 2; ++nf) {
      bLo[nf] = *(const i32x4*)&sBb[(wn * 2 + nf) * 2048 + l * 16];
      bHi[nf] = *(const i32x4*)&sBb[(wn * 2 + nf) * 2048 + 1024 + l * 16];
    }
    __builtin_amdgcn_sched_barrier(0);

    // 3) MFMA cluster: 4 x 32x32x64
    __builtin_amdgcn_s_setprio(1);
    #pragma unroll
    for (int mf = 0; mf < 2; ++mf) {
      const i32x8 af = (i32x8){aLo[mf][0], aLo[mf][1], aLo[mf][2], aLo[mf][3],
                               aHi[mf][0], aHi[mf][1], aHi[mf][2], aHi[mf][3]};
      #pragma unroll
      for (int nf = 0; nf < 2; ++nf) {
        const i32x8 bf = (i32x8){bLo[nf][0], bLo[nf][1], bLo[nf][2], bLo[nf][3],
                                 bHi[nf][0], bHi[nf][1], bHi[nf][2], bHi[nf][3]};
        acc[mf][nf] = __builtin_amdgcn_mfma_scale_f32_32x32x64_f8f6f4(
            af, bf, acc[mf][nf], 0, 0, 0, SCALE_A, 0, SCALE_B);
      }
    }
    __builtin_amdgcn_s_setprio(0);

    // 4) single drain + barrier per K-step
    asm volatile("s_waitcnt vmcnt(0)" ::: "memory");
    __builtin_amdgcn_s_barrier();
    buf ^= 1;
  }
#undef STAGE

  // ---- epilogue: two 64-row halves restaged in 32KB LDS, 512B row stores ----
  // C/D map (32x32, verified m74/m101): col=lane&31, row=(reg&3)+8*(reg>>2)+4*(lane>>5)
  float* tile = (float*)lds;   // 64 rows x 128 cols f32 = 32 KB
  #pragma unroll
  for (int half = 0; half < 2; ++half) {
    if (half) __syncthreads();          // prior stores' LDS reads complete
    if (wm == half) {
      #pragma unroll
      for (int nf = 0; nf < 2; ++nf) {
        const int col = wn * 64 + nf * 32 + (l & 31);
        const int gcol = n0 + col;
        const int sv = sid[gcol];
        const float sbv = bias[sv] - __logf(sfreq[gcol]);
        #pragma unroll
        for (int mf = 0; mf < 2; ++mf) {
          #pragma unroll
          for (int i = 0; i < 16; ++i) {
            const int r = mf * 32 + (i & 3) + 8 * (i >> 2) + 4 * (l >> 5);
            float cv = acc[mf][nf][i] + sbv;
            if (tgt[m0 + half * 64 + r] == sv) cv = NEG_INF_F;
            tile[r * 128 + (col ^ ((r & 4) << 2))] = cv;   // 2-way banks: free
          }
        }
      }
    }
    __syncthreads();
    #pragma unroll
    for (int p = 0; p < 8; ++p) {
      const int idx = p * 256 + t;
      const int r = idx >> 5;                        // local row 0..63
      const int c16 = idx & 31;                      // 16B unit within row
      f32x4 v = *(const f32x4*)&tile[r * 128 + ((c16 * 4) ^ ((r & 4) << 2))];
      *(f32x4u*)&out[(size_t)(m0 + half * 64 + r) * LCOLS + 1 + n0 + c16 * 4] = v;
    }
  }
}

// ---------------- bf16 fallback (round-1 verified), no workspace ----------------
__device__ __forceinline__ void pack8(unsigned short* p, float4 a, float4 b) {
  u16x8 v;
  v[0] = f2bf(a.x); v[1] = f2bf(a.y); v[2] = f2bf(a.z); v[3] = f2bf(a.w);
  v[4] = f2bf(b.x); v[5] = f2bf(b.y); v[6] = f2bf(b.z); v[7] = f2bf(b.w);
  *(u16x8*)p = v;
}

__global__ __launch_bounds__(256)
void k_gemm_fb(const float* __restrict__ Af, const float* __restrict__ W,
               const int* __restrict__ tgt, const int* __restrict__ sid,
               const float* __restrict__ bias, const float* __restrict__ sfreq,
               float* __restrict__ out) {
  __shared__ unsigned short sA[128 * 32];
  __shared__ unsigned short sB[128 * 32];
  const int t = threadIdx.x;
  const int w = t >> 6, l = t & 63;
  const int m0 = blockIdx.y * 128, n0 = blockIdx.x * 128;
  const int wm = w >> 1, wn = w & 1;
  f32x4 acc[4][4] = {};
  const int srow = w * 16 + (l >> 2);
  const int scol = (l & 3) * 8;

  const int id0 = sid[n0 + srow], id1 = sid[n0 + 64 + srow];
  const float* gaf0 = Af + (size_t)(m0 + srow) * HID + scol;
  const float* gaf1 = gaf0 + (size_t)64 * HID;
  const float* gbf0 = W + (size_t)id0 * HID + scol;
  const float* gbf1 = W + (size_t)id1 * HID + scol;
  for (int kk = 0; kk < HID; kk += 32) {
    float4 a0 = *(const float4*)(gaf0 + kk), a1 = *(const float4*)(gaf0 + kk + 4);
    float4 a2 = *(const float4*)(gaf1 + kk), a3 = *(const float4*)(gaf1 + kk + 4);
    float4 b0 = *(const float4*)(gbf0 + kk), b1 = *(const float4*)(gbf0 + kk + 4);
    float4 b2 = *(const float4*)(gbf1 + kk), b3 = *(const float4*)(gbf1 + kk + 4);
    __syncthreads();
    pack8(&sA[t * 8], a0, a1);
    pack8(&sA[2048 + t * 8], a2, a3);
    pack8(&sB[t * 8], b0, b1);
    pack8(&sB[2048 + t * 8], b2, b3);
    __syncthreads();
    bf16x8 af_[4], bf_[4];
    const int rl_ = l & 15, kq_ = l >> 4;
    #pragma unroll
    for (int m = 0; m < 4; m++)
      af_[m] = *(const bf16x8*)&sA[(wm * 64 + m * 16 + rl_) * 32 + kq_ * 8];
    #pragma unroll
    for (int n = 0; n < 4; n++)
      bf_[n] = *(const bf16x8*)&sB[(wn * 64 + n * 16 + rl_) * 32 + kq_ * 8];
    #pragma unroll
    for (int m = 0; m < 4; m++)
      #pragma unroll
      for (int n = 0; n < 4; n++)
        acc[m][n] = __builtin_amdgcn_mfma_f32_16x16x32_bf16(af_[m], bf_[n],
                                                            acc[m][n], 0, 0, 0);
  }
  const int rl = l & 15, rq = l >> 4;
  #pragma unroll
  for (int n = 0; n < 4; ++n) {
    const int col = n0 + wn * 64 + n * 16 + rl;
    const int sv = sid[col];
    const float sbv = bias[sv] - __logf(sfreq[col]);
    #pragma unroll
    for (int m = 0; m < 4; ++m) {
      const int rbase = m0 + wm * 64 + m * 16 + rq * 4;
      #pragma unroll
      for (int i = 0; i < 4; ++i) {
        const int r = rbase + i;
        float c = acc[m][n][i] + sbv;
        if (tgt[r] == sv) c = NEG_INF_F;
        out[(size_t)r * LCOLS + 1 + col] = c;
      }
    }
  }
}

extern "C" void kernel_launch(void* const* d_in, const int* in_sizes, int n_in,
                              void* d_out, int out_size, void* d_ws, size_t ws_size,
                              hipStream_t stream) {
  (void)in_sizes; (void)n_in; (void)out_size;
  const float* output      = (const float*)d_in[0];
  const int*   targets     = (const int*)d_in[1];
  const int*   sample_ids  = (const int*)d_in[2];
  const float* true_freq   = (const float*)d_in[3];
  const float* sample_freq = (const float*)d_in[4];
  const float* weight      = (const float*)d_in[5];
  const float* bias        = (const float*)d_in[6];
  float* out = (float*)d_out;

  const size_t needA = (size_t)NROWS * HID;   // 8 MB fp8
  const size_t needB = (size_t)NSAMP * HID;   // 8 MB fp8
  const bool use_ws = ws_size >= (needA + needB);

  k_true<<<NROWS / 4, 256, 0, stream>>>(output, targets, weight, bias, true_freq, out);

  dim3 grid(NSAMP / 128, NROWS / 128);
  if (use_ws) {
    unsigned char* Ab = (unsigned char*)d_ws;
    unsigned char* Bb = Ab + needA;
    k_cvtA<<<2048, 256, 0, stream>>>(output, Ab);
    k_gatherB<<<2048, 256, 0, stream>>>(weight, sample_ids, Bb);
    k_gemm8<<<grid, 256, 0, stream>>>(Ab, Bb, targets, sample_ids, bias,
                                      sample_freq, out);
  } else {
    k_gemm_fb<<<grid, 256, 0, stream>>>(output, weight, targets, sample_ids,
                                        bias, sample_freq, out);
  }
}